// Round 1
// baseline (23.524 us; speedup 1.0000x reference)
//
#include <hip/hip_runtime.h>

#define NFFT    512
#define NBINS   257
#define HOP     256
#define NFRAMES 511
#define TSAMP   131072
#define WINLEN  (NFFT + HOP - 1)   // 767

// One block per (batch, frame). 256 threads.
// Phase 1: stage mag = exp(log_mag[b,f,:]) and the 767-sample ex window in LDS.
// Phase 2: each thread generates FIR taps n=tid and n=tid+256 via a cos rotation
//          recurrence (A(n) = sum_m (-1)^m mag_m cos(m*theta_n)).
// Phase 3: each thread computes one output sample: 512-tap dot product from LDS.
__global__ __launch_bounds__(256)
void ltv_fir(const float* __restrict__ ex,
             const float* __restrict__ log_mag,
             float* __restrict__ out)
{
    __shared__ float s_mag[NBINS];
    __shared__ float s_ker[NFFT];
    __shared__ float s_ex[WINLEN];

    const int tid = threadIdx.x;
    const int bf  = blockIdx.x;            // 0..1021
    const int b   = bf / NFRAMES;
    const int f   = bf - b * NFRAMES;

    // ---- stage mag = exp(log_mag[b, f, 0:257]) ----
    const float* lm = log_mag + ((size_t)b * 512 + f) * NBINS;
    for (int i = tid; i < NBINS; i += 256)
        s_mag[i] = __expf(lm[i]);

    // ---- stage ex window: padded indices f*256-255 .. f*256+511 ----
    const float* exb = ex + (size_t)b * TSAMP;
    const int base = f * HOP - (NFFT / 2 - 1);   // f*256 - 255
    for (int i = tid; i < WINLEN; i += 256) {
        int g = base + i;
        s_ex[i] = (g >= 0 && g < TSAMP) ? exb[g] : 0.0f;
    }
    __syncthreads();

    // ---- FIR kernel generation ----
    // theta_n = 2*pi*n/512 ; thread handles n=tid and n=tid+256.
    const float theta = 3.14159265358979323846f * (float)tid * (1.0f / 256.0f);
    float cs, sn;
    sincosf(theta, &sn, &cs);

    // rotation recurrence: (c,s) = (cos(m*theta), sin(m*theta))
    float c = 1.0f, s = 0.0f;
    float E = 0.0f, O = 0.0f;   // even-m / odd-m partial sums of mag_m*cos(m*theta)
    #pragma unroll 8
    for (int m = 0; m < 256; m += 2) {
        E = fmaf(s_mag[m], c, E);
        float c1 = fmaf(c, cs, -(s * sn));
        float s1 = fmaf(s, cs,  (c * sn));
        O = fmaf(s_mag[m + 1], c1, O);
        float c2 = fmaf(c1, cs, -(s1 * sn));
        float s2 = fmaf(s1, cs,  (c1 * sn));
        c = c2; s = s2;
    }
    E = fmaf(s_mag[256], c, E);   // m = 256 (even)

    const float mag0   = s_mag[0];
    const float mag256 = s_mag[256];
    const float sgn    = (tid & 1) ? -1.0f : 1.0f;
    const float corr   = mag0 + sgn * mag256;
    const float inv    = 1.0f / (float)NFFT;
    // hann[n] = 0.5*(1 - cos(theta_n)); cos(theta_{tid}) = cs, cos(theta_{tid+256}) = -cs
    const float h_lo = 0.5f * (1.0f - cs);
    const float h_hi = 0.5f * (1.0f + cs);
    // A(tid) = E - O ; A(tid+256) = E + O ; (-1)^n same sign for both
    s_ker[tid]       = (2.0f * (E - O) - corr) * h_lo * inv;
    s_ker[tid + 256] = (2.0f * (E + O) - corr) * h_hi * inv;
    __syncthreads();

    // ---- convolution: out[b, f*256 + tid] = sum_k s_ex[tid+k] * s_ker[k] ----
    float acc = 0.0f;
    #pragma unroll 8
    for (int k = 0; k < NFFT; ++k)
        acc = fmaf(s_ex[tid + k], s_ker[k], acc);

    out[((size_t)b * NFRAMES + f) * HOP + tid] = acc;
}

extern "C" void kernel_launch(void* const* d_in, const int* in_sizes, int n_in,
                              void* d_out, int out_size, void* d_ws, size_t ws_size,
                              hipStream_t stream)
{
    const float* ex      = (const float*)d_in[0];
    const float* log_mag = (const float*)d_in[1];
    float* out = (float*)d_out;

    dim3 grid(2 * NFRAMES);   // B * n_frames = 1022 blocks
    dim3 block(256);
    hipLaunchKernelGGL(ltv_fir, grid, block, 0, stream, ex, log_mag, out);
}

// Round 2
// 18.655 us; speedup vs baseline: 1.2610x; 1.2610x over previous
//
#include <hip/hip_runtime.h>

#define NFFT    512
#define NBINS   257
#define HOP     256
#define NFRAMES 511
#define TSAMP   131072
#define WINLEN  767

// One block per (batch, frame). 256 threads = 4 waves.
// Phase 1: stage mag = exp(log_mag) and the 767-sample ex window in LDS.
// Phase 2: fold bins m / 256-m into parity coefficients d_e/d_o (129 entries).
// Phase 3: each thread generates taps n=tid, n=tid+256 via a 65-step Chebyshev
//          pair recurrence (4 FMA + 1 ds_read_b64 per step).
// Phase 4: conv split 4-ways over k; each lane computes 4 outputs with a
//          register sliding window (2 ds_read_b128 per 16 FMA).
// Phase 5: combine 4 partials, store.
__global__ __launch_bounds__(256)
void ltv_fir(const float* __restrict__ ex,
             const float* __restrict__ log_mag,
             float* __restrict__ out)
{
    __shared__ float s_mag[NBINS];
    __shared__ float s_de[130];          // even-parity coeffs, d[0]=d[129]=0
    __shared__ float s_do[130];          // odd-parity coeffs
    __shared__ float s_ker[NFFT];
    __shared__ float s_ex[768];          // 767 used + 1 pad for last b128 read
    __shared__ float s_part[4][256];

    const int tid = threadIdx.x;
    const int bf  = blockIdx.x;          // 0..1021
    const int b   = bf / NFRAMES;
    const int f   = bf - b * NFRAMES;

    // ---- stage mag = exp(log_mag[b, f, 0:257]) ----  (log_mag rows = 512)
    const float* lm = log_mag + ((size_t)b * 512 + f) * NBINS;
    for (int i = tid; i < NBINS; i += 256)
        s_mag[i] = __expf(lm[i]);

    // ---- stage ex window: padded indices f*256-255 .. f*256+511 ----
    const float* exb = ex + (size_t)b * TSAMP;
    const int base = f * HOP - 255;
    for (int i = tid; i < WINLEN; i += 256) {
        int g = base + i;
        s_ex[i] = (g >= 0 && g < TSAMP) ? exb[g] : 0.0f;
    }
    __syncthreads();

    // ---- fold bins: d_p[m] = (-1)^m (mag_m + p*mag_{256-m}), m=1..127;
    //      d[128] = mag_128 (self-paired, both parities); d[0]=d[129]=0 ----
    if (tid < 130) {
        float ve, vo;
        if (tid == 0 || tid == 129) {
            ve = vo = 0.0f;
        } else if (tid == 128) {
            ve = vo = s_mag[128];
        } else {
            float a = s_mag[tid], c = s_mag[256 - tid];
            float sgn = (tid & 1) ? -1.0f : 1.0f;
            ve = sgn * (a + c);
            vo = sgn * (a - c);
        }
        s_de[tid] = ve;
        s_do[tid] = vo;
    }
    __syncthreads();

    // ---- FIR kernel generation: taps n=tid and n=tid+256 ----
    {
        const float theta = 3.14159265358979323846f * (float)tid * (1.0f / 256.0f);
        const float t  = cosf(theta);          // cos(theta_n)
        const float k2 = 2.0f * t;
        const float* dsel = (tid & 1) ? s_do : s_de;
        float ce = 1.0f;   // cos(0*theta)
        float co = t;      // cos(1*theta)
        float E = 0.0f, O = 0.0f;
        #pragma unroll 5
        for (int m = 0; m < 130; m += 2) {
            float2 dd = *(const float2*)&dsel[m];
            E = fmaf(dd.x, ce, E);
            O = fmaf(dd.y, co, O);
            float ce2 = fmaf(k2, co,  -ce);    // cos((m+2)theta)
            float co2 = fmaf(k2, ce2, -co);    // cos((m+3)theta)
            ce = ce2; co = co2;
        }
        const float p    = (tid & 1) ? -1.0f : 1.0f;
        const float cst  = s_mag[0] + p * s_mag[256];
        const float inv  = 1.0f / 512.0f;
        const float h_lo = 0.5f * (1.0f - t);
        const float h_hi = 0.5f * (1.0f + t);
        s_ker[tid]       = (cst + 2.0f * (E + O)) * h_lo * inv;
        s_ker[tid + 256] = (cst + 2.0f * (E - O)) * h_hi * inv;
    }
    __syncthreads();

    // ---- conv partials: group g covers k in [g*128, g*128+128);
    //      lane computes outputs j = lane*4 + r, r=0..3 ----
    {
        const int g     = tid >> 6;
        const int lane  = tid & 63;
        const int ebase = lane * 4 + g * 128;
        const int kbase = g * 128;
        float a0 = 0.0f, a1 = 0.0f, a2 = 0.0f, a3 = 0.0f;
        float4 q0 = *(const float4*)&s_ex[ebase];
        #pragma unroll 4
        for (int kc = 0; kc < 128; kc += 4) {
            float4 q1 = *(const float4*)&s_ex[ebase + kc + 4];
            float4 kq = *(const float4*)&s_ker[kbase + kc];
            a0 = fmaf(q0.x, kq.x, fmaf(q0.y, kq.y, fmaf(q0.z, kq.z, fmaf(q0.w, kq.w, a0))));
            a1 = fmaf(q0.y, kq.x, fmaf(q0.z, kq.y, fmaf(q0.w, kq.z, fmaf(q1.x, kq.w, a1))));
            a2 = fmaf(q0.z, kq.x, fmaf(q0.w, kq.y, fmaf(q1.x, kq.z, fmaf(q1.y, kq.w, a2))));
            a3 = fmaf(q0.w, kq.x, fmaf(q1.x, kq.y, fmaf(q1.y, kq.z, fmaf(q1.z, kq.w, a3))));
            q0 = q1;
        }
        *(float4*)&s_part[g][lane * 4] = make_float4(a0, a1, a2, a3);
    }
    __syncthreads();

    // ---- combine + store ----
    float r = s_part[0][tid] + s_part[1][tid] + s_part[2][tid] + s_part[3][tid];
    out[((size_t)b * NFRAMES + f) * HOP + tid] = r;
}

extern "C" void kernel_launch(void* const* d_in, const int* in_sizes, int n_in,
                              void* d_out, int out_size, void* d_ws, size_t ws_size,
                              hipStream_t stream)
{
    const float* ex      = (const float*)d_in[0];
    const float* log_mag = (const float*)d_in[1];
    float* out = (float*)d_out;

    dim3 grid(2 * NFRAMES);   // B * n_frames = 1022 blocks
    dim3 block(256);
    hipLaunchKernelGGL(ltv_fir, grid, block, 0, stream, ex, log_mag, out);
}

// Round 3
// 13.353 us; speedup vs baseline: 1.7616x; 1.3970x over previous
//
#include <hip/hip_runtime.h>

#define NFFT    512
#define NBINS   257
#define HOP     256
#define NFRAMES 511
#define TSAMP   131072

// Swizzled s_ex addressing: +4 floats of pad per 32-float row.
// Keeps 16B alignment (i%4==0 -> SWZ(i)%4==0) and quad contiguity
// (quads never straddle a 32-float row when i%4==0), spreads the
// stride-32B lane pattern across banks at the balanced 8-phase minimum.
__device__ __forceinline__ int SWZ(int i) { return i + ((i >> 5) << 2); }

// One block per (batch, frame). 256 threads = 4 waves.
// Phase 1: stage mag = exp(log_mag) and swizzled 768-sample ex window.
// Phase 2: fold bins m / 256-m into parity coefficient arrays (132 entries).
// Phase 3: gen with parity-per-wave taps: waves 0,1 do even n, 2,3 odd n ->
//          coefficient reads are wave-uniform b128 broadcasts (33 per thread).
// Phase 4: conv, 8 k-groups x 32 threads, 8 outputs/thread, sliding 12-float
//          register window: 1 ex quad + 1 ker quad per 32 FMA.
// Phase 5: combine 8 partials, store.
__global__ __launch_bounds__(256)
void ltv_fir(const float* __restrict__ ex,
             const float* __restrict__ log_mag,
             float* __restrict__ out)
{
    __shared__ float s_mag[NBINS];
    __shared__ float s_de[132];          // even-parity coeffs, [0]=[129..131]=0
    __shared__ float s_do[132];          // odd-parity coeffs
    __shared__ float s_ker[NFFT];
    __shared__ float s_ex[860];          // SWZ(767)=859
    __shared__ float s_part[8][260];     // 260 stride: halves hit disjoint banks

    const int tid = threadIdx.x;
    const int bf  = blockIdx.x;          // 0..1021
    const int b   = bf / NFRAMES;
    const int f   = bf - b * NFRAMES;

    // ---- stage mag = exp(log_mag[b, f, 0:257]) ----  (log_mag rows = 512)
    const float* lm = log_mag + ((size_t)b * 512 + f) * NBINS;
    for (int i = tid; i < NBINS; i += 256)
        s_mag[i] = __expf(lm[i]);

    // ---- stage ex window (swizzled): padded indices f*256-255 .. f*256+512 ----
    const float* exb = ex + (size_t)b * TSAMP;
    const int base = f * HOP - 255;
    for (int i = tid; i < 768; i += 256) {
        int g = base + i;
        s_ex[SWZ(i)] = (g >= 0 && g < TSAMP) ? exb[g] : 0.0f;
    }
    __syncthreads();

    // ---- fold bins: d_p[m] = (-1)^m (mag_m + p*mag_{256-m}), m=1..127;
    //      d[128] = mag_128; d[0] = d[129..131] = 0 ----
    if (tid < 132) {
        float ve, vo;
        if (tid == 0 || tid >= 129) {
            ve = vo = 0.0f;
        } else if (tid == 128) {
            ve = vo = s_mag[128];
        } else {
            float a = s_mag[tid], c = s_mag[256 - tid];
            float sgn = (tid & 1) ? -1.0f : 1.0f;
            ve = sgn * (a + c);
            vo = sgn * (a - c);
        }
        s_de[tid] = ve;
        s_do[tid] = vo;
    }
    __syncthreads();

    // ---- FIR kernel generation, parity-per-wave ----
    {
        const int wid = tid >> 6;
        const int l   = tid & 63;
        const int par = wid >> 1;                    // 0: even n, 1: odd n
        const int n   = (((wid & 1) << 6) + l) * 2 + par;   // 0..255, one parity/wave
        const float theta = 3.14159265358979323846f * (float)n * (1.0f / 256.0f);
        const float t  = cosf(theta);
        const float k2 = 2.0f * t;
        const float* dsel = par ? s_do : s_de;       // wave-uniform pointer
        float ce = 1.0f;    // cos(m*theta),   m even slot
        float co = t;       // cos((m+1)*theta)
        float E = 0.0f, O = 0.0f;
        #pragma unroll 3
        for (int m = 0; m < 132; m += 4) {
            float4 dd = *(const float4*)&dsel[m];    // uniform b128 broadcast
            E = fmaf(dd.x, ce, E);
            O = fmaf(dd.y, co, O);
            float ce2 = fmaf(k2, co,  -ce);          // cos((m+2)theta)
            float co2 = fmaf(k2, ce2, -co);          // cos((m+3)theta)
            E = fmaf(dd.z, ce2, E);
            O = fmaf(dd.w, co2, O);
            ce = fmaf(k2, co2, -ce2);                // cos((m+4)theta)
            co = fmaf(k2, ce,  -co2);                // cos((m+5)theta)
        }
        const float p    = par ? -1.0f : 1.0f;
        const float cst  = s_mag[0] + p * s_mag[256];
        const float inv  = 1.0f / 512.0f;
        const float h_lo = 0.5f * (1.0f - t);
        const float h_hi = 0.5f * (1.0f + t);
        s_ker[n]       = (cst + 2.0f * (E + O)) * h_lo * inv;
        s_ker[n + 256] = (cst + 2.0f * (E - O)) * h_hi * inv;
    }
    __syncthreads();

    // ---- conv partials: group g covers taps [g*64, g*64+64);
    //      thread (g, lg) computes outputs j = lg*8 + r, r=0..7 ----
    {
        const int g   = tid >> 5;
        const int lg  = tid & 31;
        const int kb  = g * 64;
        const int q0i = lg * 8 + kb;     // ex window base for this thread
        float acc[8];
        #pragma unroll
        for (int r = 0; r < 8; ++r) acc[r] = 0.0f;
        float w[12];
        *(float4*)&w[0] = *(const float4*)&s_ex[SWZ(q0i)];
        *(float4*)&w[4] = *(const float4*)&s_ex[SWZ(q0i + 4)];
        #pragma unroll
        for (int kc = 0; kc < 64; kc += 4) {
            *(float4*)&w[8] = *(const float4*)&s_ex[SWZ(q0i + kc + 8)];
            float4 kq = *(const float4*)&s_ker[kb + kc];   // 2-addr broadcast
            #pragma unroll
            for (int r = 0; r < 8; ++r) {
                acc[r] = fmaf(w[r + 0], kq.x, acc[r]);
                acc[r] = fmaf(w[r + 1], kq.y, acc[r]);
                acc[r] = fmaf(w[r + 2], kq.z, acc[r]);
                acc[r] = fmaf(w[r + 3], kq.w, acc[r]);
            }
            #pragma unroll
            for (int i = 0; i < 8; ++i) w[i] = w[i + 4];
        }
        #pragma unroll
        for (int r = 0; r < 8; ++r) s_part[g][lg * 8 + r] = acc[r];
    }
    __syncthreads();

    // ---- combine + store ----
    float r = 0.0f;
    #pragma unroll
    for (int g2 = 0; g2 < 8; ++g2) r += s_part[g2][tid];
    out[((size_t)b * NFRAMES + f) * HOP + tid] = r;
}

extern "C" void kernel_launch(void* const* d_in, const int* in_sizes, int n_in,
                              void* d_out, int out_size, void* d_ws, size_t ws_size,
                              hipStream_t stream)
{
    const float* ex      = (const float*)d_in[0];
    const float* log_mag = (const float*)d_in[1];
    float* out = (float*)d_out;

    dim3 grid(2 * NFRAMES);   // B * n_frames = 1022 blocks
    dim3 block(256);
    hipLaunchKernelGGL(ltv_fir, grid, block, 0, stream, ex, log_mag, out);
}

// Round 4
// 12.942 us; speedup vs baseline: 1.8177x; 1.0318x over previous
//
#include <hip/hip_runtime.h>

#define NFFT    512
#define NBINS   257
#define HOP     256
#define NFRAMES 511
#define TSAMP   131072

// +4 floats of pad per 32-float row: keeps 16B alignment and quad contiguity
// for i%4==0, spreads strided lane patterns to the balanced-bank minimum.
__device__ __forceinline__ int SWZ(int i) { return i + ((i >> 5) << 2); }

// One block per (batch, frame). 256 threads = 4 waves, 3 barriers.
// Phase 1 (parallel): tid<192 stage ex window (aligned float4 global loads,
//   scalar swizzled LDS stores absorb the -255 offset); tid>=192 fold bins
//   m/256-m into parity coefficient arrays, reading log_mag directly.
// Phase 2: gen on 129 threads. K symmetry (K[256-u]=K[256+u], K[0]=0) +
//   (n,n+256) pairing => one 65-step Chebyshev (E,O) gives 4 taps.
// Phase 3: conv, 16 k-groups x 16 threads, 16 outputs/thread, sliding
//   20-float register window: 12 ex + 8 ker b128 per 512 FMA.
// Phase 4: combine 16 partials, store.
__global__ __launch_bounds__(256)
void ltv_fir(const float* __restrict__ ex,
             const float* __restrict__ log_mag,
             float* __restrict__ out)
{
    __shared__ float s_d[2][132];        // [parity][m], [*][0]=[*][129..131]=0
    __shared__ float s_c[2];             // mag[0], mag[256]
    __shared__ float s_ker[512];
    __shared__ float s_ex[864];          // SWZ(767)=859
    __shared__ float s_part[16][260];

    const int tid = threadIdx.x;
    const int bf  = blockIdx.x;          // 0..1021
    const int b   = bf / NFRAMES;
    const int f   = bf - b * NFRAMES;

    const float* lm  = log_mag + ((size_t)b * 512 + f) * NBINS;
    const float* exb = ex + (size_t)b * TSAMP;

    // ---- phase 1: stage ex (tid<192) || fold coefficients (tid>=192) ----
    if (tid < 192) {
        const int gw = f * HOP - 256 + tid * 4;   // aligned global word base
        float4 q = make_float4(0.f, 0.f, 0.f, 0.f);
        if (gw >= 0) q = *(const float4*)&exb[gw];   // right edge always in range
        const int wb = tid * 4 - 1;                  // window idx of q.x
        if (tid > 0) s_ex[SWZ(wb)] = q.x;
        s_ex[SWZ(wb + 1)] = q.y;
        s_ex[SWZ(wb + 2)] = q.z;
        s_ex[SWZ(wb + 3)] = q.w;
    } else {
        #pragma unroll
        for (int it = 0; it < 3; ++it) {
            const int s2 = (tid - 192) + 64 * it;
            if (s2 < 134) {
                if (s2 == 132)      s_c[0] = __expf(lm[0]);
                else if (s2 == 133) s_c[1] = __expf(lm[256]);
                else if (s2 == 0 || s2 >= 129) { s_d[0][s2] = 0.f; s_d[1][s2] = 0.f; }
                else if (s2 == 128) { const float v = __expf(lm[128]); s_d[0][128] = v; s_d[1][128] = v; }
                else {
                    const float a  = __expf(lm[s2]);
                    const float c0 = __expf(lm[256 - s2]);
                    const float sg = (s2 & 1) ? -1.f : 1.f;
                    s_d[0][s2] = sg * (a + c0);   // even-parity taps
                    s_d[1][s2] = sg * (a - c0);   // odd-parity taps
                }
            }
        }
    }
    __syncthreads();

    // ---- phase 2: FIR kernel gen, 4 taps per (E,O) ----
    if (tid <= 128) {
        const int wid  = tid >> 6;
        const int lane = tid & 63;
        const int n    = (wid == 2) ? 128 : 2 * lane + wid;   // parity uniform/wave
        const float t  = __cosf(3.14159265358979323846f * (float)n * (1.0f / 256.0f));
        const float k2 = 2.0f * t;
        const float* dsel = s_d[n & 1];                       // wave-uniform ptr
        float ce = 1.0f, co = t, E = 0.0f, O = 0.0f;
        #pragma unroll 3
        for (int m = 0; m < 132; m += 4) {
            float4 dd = *(const float4*)&dsel[m];             // uniform b128 bcast
            E = fmaf(dd.x, ce, E);
            O = fmaf(dd.y, co, O);
            float ce2 = fmaf(k2, co,  -ce);
            float co2 = fmaf(k2, ce2, -co);
            E = fmaf(dd.z, ce2, E);
            O = fmaf(dd.w, co2, O);
            ce = fmaf(k2, co2, -ce2);
            co = fmaf(k2, ce,  -co2);
        }
        const float p    = (n & 1) ? -1.f : 1.f;
        const float cst  = s_c[0] + p * s_c[1];
        const float v_lo = (cst + 2.f * (E + O)) * (0.5f * (1.f - t)) * (1.f / 512.f);
        const float v_hi = (cst + 2.f * (E - O)) * (0.5f * (1.f + t)) * (1.f / 512.f);
        s_ker[n]       = v_lo;                    // K[n]
        s_ker[256 - n] = v_hi;                    // K[256-n] = K[256+n]
        if (n > 0) { s_ker[256 + n] = v_hi; s_ker[512 - n] = v_lo; }
    }
    __syncthreads();

    // ---- phase 3: conv partials; group g: taps [g*32, g*32+32),
    //      thread (g,lt): outputs j = lt*16 + r ----
    {
        const int g   = tid >> 4;
        const int lt  = tid & 15;
        const int kb  = g * 32;
        const int off = kb + lt * 16;             // ex window base for thread
        float w[20];
        #pragma unroll
        for (int c = 0; c < 5; ++c)
            *(float4*)&w[4 * c] = *(const float4*)&s_ex[SWZ(off + 4 * c)];
        float acc[16];
        #pragma unroll
        for (int r = 0; r < 16; ++r) acc[r] = 0.0f;
        #pragma unroll
        for (int kc = 0; kc < 32; kc += 4) {
            const float4 kq = *(const float4*)&s_ker[kb + kc];   // 4-addr bcast
            #pragma unroll
            for (int r = 0; r < 16; ++r)
                acc[r] = fmaf(w[r], kq.x, fmaf(w[r + 1], kq.y,
                         fmaf(w[r + 2], kq.z, fmaf(w[r + 3], kq.w, acc[r]))));
            if (kc < 28) {
                #pragma unroll
                for (int i = 0; i < 16; ++i) w[i] = w[i + 4];
                *(float4*)&w[16] = *(const float4*)&s_ex[SWZ(off + kc + 20)];
            }
        }
        #pragma unroll
        for (int c = 0; c < 4; ++c)
            *(float4*)&s_part[g][lt * 16 + 4 * c] =
                make_float4(acc[4 * c], acc[4 * c + 1], acc[4 * c + 2], acc[4 * c + 3]);
    }
    __syncthreads();

    // ---- phase 4: combine + store ----
    float r = 0.0f;
    #pragma unroll
    for (int gg = 0; gg < 16; ++gg) r += s_part[gg][tid];
    out[((size_t)b * NFRAMES + f) * HOP + tid] = r;
}

extern "C" void kernel_launch(void* const* d_in, const int* in_sizes, int n_in,
                              void* d_out, int out_size, void* d_ws, size_t ws_size,
                              hipStream_t stream)
{
    const float* ex      = (const float*)d_in[0];
    const float* log_mag = (const float*)d_in[1];
    float* out = (float*)d_out;

    dim3 grid(2 * NFRAMES);   // B * n_frames = 1022 blocks
    dim3 block(256);
    hipLaunchKernelGGL(ltv_fir, grid, block, 0, stream, ex, log_mag, out);
}